// Round 9
// baseline (219.043 us; speedup 1.0000x reference)
//
#include <hip/hip_runtime.h>

// KAN layer forward, MI355X. Inputs AND outputs are float32 buffers.
// Outputs (flat concat, f32): y_out[1024,128], preacts[1024,128,128],
// postacts[1024,128,128], postspline[1024,128,128].
//
// R13 resubmit (R8 bench was a container-acquisition failure, not a kernel
// verdict). Two kernels through d_ws (5.25 MB; guarded, with verified-R12
// single-kernel fallback):
//  - kan_basis: per (b,i) thread, verified basis+silu+x -> ws[b][10][128].
//  - kan_stream: FILL-SHAPED consumer. No LDS, no barriers, no phases:
//    wave = j-pair, 16 fully-unrolled batch rows, basis via global loads
//    (L2-hot, 5 MB shared by co-resident blocks), coef/scales in regs,
//    same dot/stores, batched py[16] butterfly at the end.
// Rationale: 8 within-structure interventions were neutral; the only code
// on this chip that sustains 6.6 TB/s (the fill) differs from ours only in
// execution SHAPE (no barrier-locked phase bunching, no LDS coupling, no
// store-burst/retire cycle). This removes exactly that difference.
// Predict: kernel ~90 -> ~50-60us, dur ~210 -> ~170-185. If neutral: all
// kernel-addressable axes exhausted -> floor declaration.

#define IN_DIM  128
#define OUT_DIM 128
#define NUMG    5
#define KORD    3
#define NB      8          // NUMG + KORD basis functions
#define SIZE    (IN_DIM * OUT_DIM)
#define BATCH   1024
#define G       8          // (fallback kernel) batch rows per block
#define JB      8          // j per block
#define NBG     (BATCH / G)
#define NJO     (OUT_DIM / JB)
#define WSROW   (10 * IN_DIM)              // floats per b in ws
#define RCHUNK  16                         // rows per kan_stream block

// ---------- basis math (shared, verified in R10-R12) ----------
__device__ __forceinline__ void basis_row(const float* __restrict__ grid,
                                          int i, float xv, float* __restrict__ B,
                                          float& silu)
{
    float gr[NUMG + 1];
    #pragma unroll
    for (int rr = 0; rr <= NUMG; ++rr) gr[rr] = grid[i * (NUMG + 1) + rr];

    const float h = (gr[NUMG] - gr[0]) * (1.0f / NUMG);
    float t[NUMG + 1 + 2 * KORD];             // 12 knots
    t[2] = gr[0] - h; t[1] = t[2] - h; t[0] = t[1] - h;
    #pragma unroll
    for (int rr = 0; rr <= NUMG; ++rr) t[KORD + rr] = gr[rr];
    t[9] = gr[NUMG] + h; t[10] = t[9] + h; t[11] = t[10] + h;

    float rcp1[11], rcp2[10], rcp3[9];
    #pragma unroll
    for (int m = 0; m < 11; ++m) rcp1[m] = 1.0f / (t[m + 1] - t[m]);
    #pragma unroll
    for (int m = 0; m < 10; ++m) rcp2[m] = 1.0f / (t[m + 2] - t[m]);
    #pragma unroll
    for (int m = 0; m < 9;  ++m) rcp3[m] = 1.0f / (t[m + 3] - t[m]);

    float Bt[NUMG + 2 * KORD];                // 11 -> 10 -> 9 -> 8
    #pragma unroll
    for (int m = 0; m < NUMG + 2 * KORD; ++m)
        Bt[m] = (xv >= t[m] && xv < t[m + 1]) ? 1.0f : 0.0f;
    #pragma unroll
    for (int m = 0; m < 10; ++m)
        Bt[m] = (xv - t[m]) * rcp1[m] * Bt[m]
              + (t[m + 2] - xv) * rcp1[m + 1] * Bt[m + 1];
    #pragma unroll
    for (int m = 0; m < 9; ++m)
        Bt[m] = (xv - t[m]) * rcp2[m] * Bt[m]
              + (t[m + 3] - xv) * rcp2[m + 1] * Bt[m + 1];
    #pragma unroll
    for (int m = 0; m < 8; ++m)
        Bt[m] = (xv - t[m]) * rcp3[m] * Bt[m]
              + (t[m + 4] - xv) * rcp3[m + 1] * Bt[m + 1];

    #pragma unroll
    for (int m = 0; m < NB; ++m) B[m] = Bt[m];
    silu = xv / (1.0f + __expf(-xv));
}

// ---------- kernel 1: basis producer (512 blocks x 256) ----------
__global__ __launch_bounds__(256) void kan_basis(
    const float* __restrict__ x,
    const float* __restrict__ grid,
    float* __restrict__ ws)
{
    const int idx = blockIdx.x * 256 + threadIdx.x;
    const int b = idx >> 7;
    const int i = idx & 127;
    const float xv = x[b * IN_DIM + i];

    float B[NB], silu;
    basis_row(grid, i, xv, B, silu);

    float* wp = ws + (size_t)b * WSROW;
    #pragma unroll
    for (int m = 0; m < NB; ++m) wp[m * IN_DIM + i] = B[m];
    wp[8 * IN_DIM + i] = silu;
    wp[9 * IN_DIM + i] = xv;
}

// ---------- kernel 2: fill-shaped streamer (1024 blocks x 256) ----------
// No LDS. No barriers. Wave = one j-pair; 16 fully-unrolled batch rows.
__global__ __launch_bounds__(256) void kan_stream(
    const float* __restrict__ ws,
    const float* __restrict__ coef,
    const float* __restrict__ scale_base,
    const float* __restrict__ scale_sp,
    const float* __restrict__ mask,
    float* __restrict__ out)
{
    const int tid  = threadIdx.x;
    const int lane = tid & 63;
    const int w    = tid >> 6;
    const int il   = lane & 31;
    const int jh   = lane >> 5;
    const int i4   = il << 2;

    const int jo = blockIdx.x & (NJO - 1);
    const int bc = blockIdx.x >> 4;           // 64 chunks of 16 rows
    const int j  = jo * JB + w * 2 + jh;

    // coef for this lane's 4 i at this j: 8 float4 = 32 regs
    float4 cfq[8];
    {
        const float4* cp = (const float4*)coef;
        #pragma unroll
        for (int q = 0; q < 8; ++q)
            cfq[q] = cp[(size_t)j * 256 + il * 8 + q];
    }
    const int sS = j * IN_DIM + i4;
    const float4 mkv = *(const float4*)&mask[sS];
    const float4 sbv = *(const float4*)&scale_base[sS];
    const float4 ssv = *(const float4*)&scale_sp[sS];

    float cfs[4][NB];
    #pragma unroll
    for (int k = 0; k < 4; ++k) {
        const float4 lo = cfq[2 * k], hi = cfq[2 * k + 1];
        cfs[k][0] = lo.x; cfs[k][1] = lo.y; cfs[k][2] = lo.z; cfs[k][3] = lo.w;
        cfs[k][4] = hi.x; cfs[k][5] = hi.y; cfs[k][6] = hi.z; cfs[k][7] = hi.w;
    }
    const float mkA[4] = {mkv.x, mkv.y, mkv.z, mkv.w};
    const float sbA[4] = {sbv.x, sbv.y, sbv.z, sbv.w};
    const float ssA[4] = {ssv.x, ssv.y, ssv.z, ssv.w};

    float* out_y   = out;
    float* out_pre = out + BATCH * OUT_DIM;
    float* out_act = out_pre + (size_t)BATCH * SIZE;
    float* out_spl = out_act + (size_t)BATCH * SIZE;

    float py[RCHUNK];

    #pragma unroll
    for (int r = 0; r < RCHUNK; ++r) {
        const int b_r = bc * RCHUNK + r;
        const float* wp = ws + (size_t)b_r * WSROW;

        float4 bas[NB];
        #pragma unroll
        for (int m = 0; m < NB; ++m)
            bas[m] = *(const float4*)&wp[m * IN_DIM + i4];
        const float4 slv = *(const float4*)&wp[8 * IN_DIM + i4];
        const float4 pxv = *(const float4*)&wp[9 * IN_DIM + i4];

        float sp0 = cfs[0][0] * bas[0].x;
        float sp1 = cfs[1][0] * bas[0].y;
        float sp2 = cfs[2][0] * bas[0].z;
        float sp3 = cfs[3][0] * bas[0].w;
        #pragma unroll
        for (int m = 1; m < NB; ++m) {
            const float4 b4 = bas[m];
            sp0 = fmaf(cfs[0][m], b4.x, sp0);
            sp1 = fmaf(cfs[1][m], b4.y, sp1);
            sp2 = fmaf(cfs[2][m], b4.z, sp2);
            sp3 = fmaf(cfs[3][m], b4.w, sp3);
        }

        const float spA[4] = {sp0, sp1, sp2, sp3};
        const float slA[4] = {slv.x, slv.y, slv.z, slv.w};
        float y[4];
        #pragma unroll
        for (int k = 0; k < 4; ++k)
            y[k] = mkA[k] * (sbA[k] * slA[k] + ssA[k] * spA[k]);

        const size_t e = (size_t)b_r * SIZE + (size_t)sS;
        *(float4*)&out_pre[e] = pxv;
        *(float4*)&out_act[e] = make_float4(y[0], y[1], y[2], y[3]);
        *(float4*)&out_spl[e] = make_float4(spA[0], spA[1], spA[2], spA[3]);

        py[r] = (y[0] + y[1]) + (y[2] + y[3]);
    }

    #pragma unroll
    for (int off = 16; off > 0; off >>= 1) {
        #pragma unroll
        for (int r = 0; r < RCHUNK; ++r)
            py[r] += __shfl_down(py[r], off, 32);
    }
    if (il == 0) {
        #pragma unroll
        for (int r = 0; r < RCHUNK; ++r)
            out_y[(bc * RCHUNK + r) * OUT_DIM + j] = py[r];
    }
}

// ---------- fallback: verified R12 single-kernel ----------
__global__ __launch_bounds__(256) void kan_fused(
    const float* __restrict__ x,
    const float* __restrict__ grid,
    const float* __restrict__ coef,
    const float* __restrict__ scale_base,
    const float* __restrict__ scale_sp,
    const float* __restrict__ mask,
    float* __restrict__ out)
{
    __shared__ float sBT[G][NB][IN_DIM];
    __shared__ float sSilu[G][IN_DIM];
    __shared__ float sXv[G][IN_DIM];

    const int tid = threadIdx.x;
    const int bg  = blockIdx.x >> 4;
    const int jo  = blockIdx.x & (NJO - 1);

    const int lane = tid & 63;
    const int w    = tid >> 6;
    const int il   = lane & 31;
    const int jh   = lane >> 5;
    const int i4   = il << 2;
    const int j    = jo * JB + w * 2 + jh;

    float4 cfq[8];
    {
        const float4* cp = (const float4*)coef;
        #pragma unroll
        for (int q = 0; q < 8; ++q)
            cfq[q] = cp[(size_t)j * 256 + il * 8 + q];
    }
    const int sS = j * IN_DIM + i4;
    const float4 mkv = *(const float4*)&mask[sS];
    const float4 sbv = *(const float4*)&scale_base[sS];
    const float4 ssv = *(const float4*)&scale_sp[sS];

    {
        const int i  = tid & 127;
        const int r0 = tid >> 7;
        #pragma unroll
        for (int it = 0; it < 4; ++it) {
            const int r = it * 2 + r0;
            const float xv = x[(bg * G + r) * IN_DIM + i];
            float B[NB], silu;
            basis_row(grid, i, xv, B, silu);
            #pragma unroll
            for (int m = 0; m < NB; ++m) sBT[r][m][i] = B[m];
            sSilu[r][i] = silu;
            sXv[r][i]   = xv;
        }
    }
    __syncthreads();

    float cfs[4][NB];
    #pragma unroll
    for (int k = 0; k < 4; ++k) {
        const float4 lo = cfq[2 * k], hi = cfq[2 * k + 1];
        cfs[k][0] = lo.x; cfs[k][1] = lo.y; cfs[k][2] = lo.z; cfs[k][3] = lo.w;
        cfs[k][4] = hi.x; cfs[k][5] = hi.y; cfs[k][6] = hi.z; cfs[k][7] = hi.w;
    }
    const float mkA[4] = {mkv.x, mkv.y, mkv.z, mkv.w};
    const float sbA[4] = {sbv.x, sbv.y, sbv.z, sbv.w};
    const float ssA[4] = {ssv.x, ssv.y, ssv.z, ssv.w};

    float* out_y   = out;
    float* out_pre = out + BATCH * OUT_DIM;
    float* out_act = out_pre + (size_t)BATCH * SIZE;
    float* out_spl = out_act + (size_t)BATCH * SIZE;

    float py[G];
    #pragma unroll
    for (int r = 0; r < G; ++r) {
        float4 bas[NB];
        #pragma unroll
        for (int m = 0; m < NB; ++m)
            bas[m] = *(const float4*)&sBT[r][m][i4];

        float sp0 = cfs[0][0] * bas[0].x;
        float sp1 = cfs[1][0] * bas[0].y;
        float sp2 = cfs[2][0] * bas[0].z;
        float sp3 = cfs[3][0] * bas[0].w;
        #pragma unroll
        for (int m = 1; m < NB; ++m) {
            const float4 b4 = bas[m];
            sp0 = fmaf(cfs[0][m], b4.x, sp0);
            sp1 = fmaf(cfs[1][m], b4.y, sp1);
            sp2 = fmaf(cfs[2][m], b4.z, sp2);
            sp3 = fmaf(cfs[3][m], b4.w, sp3);
        }

        const float4 slv = *(const float4*)&sSilu[r][i4];
        const float4 pxv = *(const float4*)&sXv[r][i4];
        const float spA[4] = {sp0, sp1, sp2, sp3};
        const float slA[4] = {slv.x, slv.y, slv.z, slv.w};
        float y[4];
        #pragma unroll
        for (int k = 0; k < 4; ++k)
            y[k] = mkA[k] * (sbA[k] * slA[k] + ssA[k] * spA[k]);

        const int b_r = bg * G + r;
        const size_t e = (size_t)b_r * SIZE + (size_t)sS;
        *(float4*)&out_pre[e] = pxv;
        *(float4*)&out_act[e] = make_float4(y[0], y[1], y[2], y[3]);
        *(float4*)&out_spl[e] = make_float4(spA[0], spA[1], spA[2], spA[3]);

        py[r] = (y[0] + y[1]) + (y[2] + y[3]);
    }

    #pragma unroll
    for (int off = 16; off > 0; off >>= 1) {
        #pragma unroll
        for (int r = 0; r < G; ++r)
            py[r] += __shfl_down(py[r], off, 32);
    }
    if (il == 0) {
        #pragma unroll
        for (int r = 0; r < G; ++r)
            out_y[(bg * G + r) * OUT_DIM + j] = py[r];
    }
}

extern "C" void kernel_launch(void* const* d_in, const int* in_sizes, int n_in,
                              void* d_out, int out_size, void* d_ws, size_t ws_size,
                              hipStream_t stream)
{
    const size_t WS_NEED = (size_t)BATCH * WSROW * sizeof(float); // 5.25 MB
    if (d_ws != nullptr && ws_size >= WS_NEED) {
        hipLaunchKernelGGL(kan_basis, dim3(BATCH * IN_DIM / 256), dim3(256), 0,
                           stream,
                           (const float*)d_in[0], (const float*)d_in[1],
                           (float*)d_ws);
        hipLaunchKernelGGL(kan_stream, dim3((BATCH / RCHUNK) * NJO), dim3(256),
                           0, stream,
                           (const float*)d_ws, (const float*)d_in[2],
                           (const float*)d_in[3], (const float*)d_in[4],
                           (const float*)d_in[5], (float*)d_out);
    } else {
        hipLaunchKernelGGL(kan_fused, dim3(NJO * NBG), dim3(256), 0, stream,
                           (const float*)d_in[0], (const float*)d_in[1],
                           (const float*)d_in[2], (const float*)d_in[3],
                           (const float*)d_in[4], (const float*)d_in[5],
                           (float*)d_out);
    }
}